// Round 13
// baseline (219.986 us; speedup 1.0000x reference)
//
#include <hip/hip_runtime.h>
#include <math.h>

#define Bc 4
#define Nc 6
#define Dc 59
#define FHc 16
#define FWc 44
#define Cc 64
#define OCc 123   // D + OUT_C
#define NXc 128
#define NYc 128
#define NVOX (Bc*NXc*NYc)         // 65536
#define NBLK (Bc*Nc*FWc)          // 1056 (cam, wi) pairs
#define NBLK2 (NBLK*2)            // 2112 blocks: (cam, wi, d-half)

// ws layout: acc[65536][64] f32 (16 MB); camMat[24][2][18]; wdT2[64][128] interleaved
#define WS_ACC 0
#define WS_CAM ((size_t)16777216)
#define WS_WDT ((size_t)16781312)

template<bool FMA>
__device__ __forceinline__ float mulsub(float a, float b, float c) {
    if (FMA) return __fmaf_rn(-a, b, c);
    return __fadd_rn(c, __fmul_rn(-a, b));
}

// numpy.linalg.inv mirror: LAPACK sgesv on the C-order buffer seen as Fortran,
// i.e. factorizes A^T (inv(A) = inv(A^T)^T). sgetf2+sgetrs, strict f32.
template<bool FMA>
__device__ __forceinline__ void lu_inv3x3T(const float* __restrict__ m, float* __restrict__ o) {
    float A[3][3] = {{m[0],m[3],m[6]},{m[1],m[4],m[7]},{m[2],m[5],m[8]}};  // A^T
    int piv0, piv1;
    {
        float a0=fabsf(A[0][0]), a1=fabsf(A[1][0]), a2=fabsf(A[2][0]);
        int p = 0; float mx = a0;
        if (a1 > mx) { mx = a1; p = 1; }
        if (a2 > mx) { mx = a2; p = 2; }
        piv0 = p;
        if (p != 0) { for (int k=0;k<3;++k){ float t=A[0][k]; A[0][k]=A[p][k]; A[p][k]=t; } }
        const float d = __fdiv_rn(1.0f, A[0][0]);
        A[1][0] = __fmul_rn(A[1][0], d);
        A[2][0] = __fmul_rn(A[2][0], d);
        #pragma unroll
        for (int i=1;i<3;++i)
            #pragma unroll
            for (int j=1;j<3;++j)
                A[i][j] = mulsub<FMA>(A[i][0], A[0][j], A[i][j]);
    }
    {
        float a1=fabsf(A[1][1]), a2=fabsf(A[2][1]);
        int p = (a2 > a1) ? 2 : 1;
        piv1 = p;
        if (p != 1) { for (int k=0;k<3;++k){ float t=A[1][k]; A[1][k]=A[p][k]; A[p][k]=t; } }
        const float d = __fdiv_rn(1.0f, A[1][1]);
        A[2][1] = __fmul_rn(A[2][1], d);
        A[2][2] = mulsub<FMA>(A[2][1], A[1][2], A[2][2]);
    }
    float B[3][3] = {{1.f,0.f,0.f},{0.f,1.f,0.f},{0.f,0.f,1.f}};
    if (piv0 != 0) { for (int k=0;k<3;++k){ float t=B[0][k]; B[0][k]=B[piv0][k]; B[piv0][k]=t; } }
    if (piv1 != 1) { for (int k=0;k<3;++k){ float t=B[1][k]; B[1][k]=B[piv1][k]; B[piv1][k]=t; } }
    #pragma unroll
    for (int j=0;j<3;++j) {
        B[1][j] = mulsub<FMA>(A[1][0], B[0][j], B[1][j]);
        B[2][j] = mulsub<FMA>(A[2][0], B[0][j], B[2][j]);
        B[2][j] = mulsub<FMA>(A[2][1], B[1][j], B[2][j]);
        B[2][j] = __fdiv_rn(B[2][j], A[2][2]);
        B[0][j] = mulsub<FMA>(A[0][2], B[2][j], B[0][j]);
        B[1][j] = mulsub<FMA>(A[1][2], B[2][j], B[1][j]);
        B[1][j] = __fdiv_rn(B[1][j], A[1][1]);
        B[0][j] = mulsub<FMA>(A[0][1], B[1][j], B[0][j]);
        B[0][j] = __fdiv_rn(B[0][j], A[0][0]);
    }
    o[0]=B[0][0]; o[1]=B[1][0]; o[2]=B[2][0];
    o[3]=B[0][1]; o[4]=B[1][1]; o[5]=B[2][1];
    o[6]=B[0][2]; o[7]=B[1][2]; o[8]=B[2][2];
}

template<bool FMA>
__device__ __forceinline__ float dot3(float a0,float a1,float a2,float b0,float b1,float b2){
    if (FMA) return __fmaf_rn(a2,b2, __fmaf_rn(a1,b1, __fmul_rn(a0,b0)));
    return __fadd_rn(__fadd_rn(__fmul_rn(a0,b0), __fmul_rn(a1,b1)), __fmul_rn(a2,b2));
}

// ---- K0: acc zeroing (full-BW float4) + wd interleave + per-(cam,var) matrices ----
// wdT2[c][2*o] = wd[o][c] (o 0..63); wdT2[c][2*o+1] = wd[o+64][c] (o 0..58), pads 0
__global__ __launch_bounds__(256) void prep(
    const float* __restrict__ wd, const float* __restrict__ rots,
    const float* __restrict__ intrins, const float* __restrict__ post_rots,
    float* __restrict__ wdT2, float* __restrict__ camMat, float4* __restrict__ acc4)
{
    const int gid = blockIdx.x*256 + threadIdx.x;   // 0..524287 (2048 blocks)
    const float4 z = make_float4(0.f, 0.f, 0.f, 0.f);
    acc4[gid] = z;
    acc4[gid + 524288] = z;                         // 2 x 524288 = 1M float4 = 16 MB

    if (gid < OCc*Cc) {
        const int o = gid >> 6, c = gid & 63;
        const int slot = (o < 64) ? (o << 1) : (((o - 64) << 1) | 1);
        wdT2[(c << 7) + slot] = wd[gid];
    } else if (gid < OCc*Cc + 320) {
        const int k = gid - OCc*Cc;                 // zero 5 pad slots per c
        const int c = k / 5, o = 59 + (k % 5);
        wdT2[(c << 7) + (o << 1) + 1] = 0.0f;
    }
    if (gid < 48) {
        const int cam = gid >> 1;
        const int var = gid & 1;
        const float* pr = post_rots + cam*9;
        const float* ro = rots      + cam*9;
        const float* it = intrins   + cam*9;
        float PRi[9], INi[9], CM[9];
        if (var == 0) { lu_inv3x3T<true >(pr, PRi); lu_inv3x3T<true >(it, INi); }
        else          { lu_inv3x3T<false>(pr, PRi); lu_inv3x3T<false>(it, INi); }
        #pragma unroll
        for (int r2 = 0; r2 < 3; ++r2)
            #pragma unroll
            for (int c2 = 0; c2 < 3; ++c2)
                CM[r2*3+c2] = dot3<true>(ro[r2*3+0], ro[r2*3+1], ro[r2*3+2],
                                         INi[0*3+c2], INi[1*3+c2], INi[2*3+c2]);
        float* dst = camMat + (size_t)(cam*2 + var)*18;
        #pragma unroll
        for (int k = 0; k < 9; ++k) { dst[k] = PRi[k]; dst[9+k] = CM[k]; }
    }
}

// Per-point geometry using precomputed PRi/CM (ops identical to R6 path)
template<bool FMA>
__device__ __forceinline__ int geom_light(
    const float* __restrict__ PRi, const float* __restrict__ CM,
    float pt0, float pt1, float pt2, float tr0, float tr1, float tr2,
    float u, float v, float dval, int b)
{
    const float p0 = __fsub_rn(u,    pt0);
    const float p1 = __fsub_rn(v,    pt1);
    const float p2 = __fsub_rn(dval, pt2);
    const float q0 = dot3<FMA>(PRi[0],PRi[1],PRi[2], p0,p1,p2);
    const float q1 = dot3<FMA>(PRi[3],PRi[4],PRi[5], p0,p1,p2);
    const float q2 = dot3<FMA>(PRi[6],PRi[7],PRi[8], p0,p1,p2);
    const float r0 = __fmul_rn(q0, q2);
    const float r1 = __fmul_rn(q1, q2);
    const float s0 = __fadd_rn(dot3<FMA>(CM[0],CM[1],CM[2], r0,r1,q2), tr0);
    const float s1 = __fadd_rn(dot3<FMA>(CM[3],CM[4],CM[5], r0,r1,q2), tr1);
    const float s2 = __fadd_rn(dot3<FMA>(CM[6],CM[7],CM[8], r0,r1,q2), tr2);
    const float CX  = -51.200000762939453f;  // f32(f32(-50.8) - f32(0.8)/2)
    const float DXf =  0.80000001192092896f; // f32(0.8)
    const float gx = __fdiv_rn(__fsub_rn(s0, CX), DXf);
    const float gy = __fdiv_rn(__fsub_rn(s1, CX), DXf);
    const float gz = __fdiv_rn(__fsub_rn(s2, -10.0f), 20.0f);
    const bool kept = (gx > -1.0f) && (gx < 128.0f) &&
                      (gy > -1.0f) && (gy < 128.0f) &&
                      (gz > -1.0f) && (gz < 1.0f);
    return kept ? (b*(NXc*NYc) + ((int)gy)*NXc + (int)gx) : -1;
}

// ---- K1: one block per (cam, wi, d-half); matvec+softmax per block (cheap,
// duplicated), geometry+scatter for 30/29 depth bins. 2112 blocks -> 33 waves/CU.
__global__ __launch_bounds__(256, 8) void lss_main(
    const float* __restrict__ x, const float* __restrict__ trans,
    const float* __restrict__ post_trans, const float* __restrict__ bd,
    const float* __restrict__ wdT2, const float* __restrict__ camMat,
    float* __restrict__ acc)
{
    const int blk2 = blockIdx.x;
    const int pixblk = blk2 >> 1;
    const int half = blk2 & 1;
    const int d0 = half * 30;            // d range [d0, d0+dn)
    const int dn = 30 - half;            // 30 or 29
    const int wi  = pixblk % FWc;
    const int cam = pixblk / FWc;        // 0..23
    const int b   = cam / Nc;
    const int t = threadIdx.x;
    const int wave = t >> 6, lane = t & 63;

    __shared__ float  xsT[64][16];    // c-major x column            (4 KB)
    __shared__ float  yv[16][60];     // y then dep in place         (3.8 KB)
    __shared__ float  ctxT[64][18];   // ch-major ctx, pad 18        (4.6 KB)
    __shared__ float4 geo[30][16];    // (dep, vA, vB, -) this half  (7.7 KB)

    // stage 1: x column gather (c-major so stage-2 can b128-broadcast 4 rows)
    {
        const float* xb = x + (size_t)cam*64*(FHc*FWc) + wi;
        for (int idx = t; idx < 1024; idx += 256) {
            const int c = idx >> 4, hi = idx & 15;
            xsT[c][hi] = xb[(size_t)c*(FHc*FWc) + hi*FWc];
        }
    }
    __syncthreads();

    // stage 2: matvec; wave handles rows hi0..hi0+3, lane = o and o+64
    // one b64 global load per c (interleaved layout); FMA chain ascending ->
    // bit-identical per-output sum order vs all previous rounds
    {
        const int hi0 = wave << 2;
        float a0[4] = {0.f,0.f,0.f,0.f}, a1[4] = {0.f,0.f,0.f,0.f};
        const float2* wrow = (const float2*)wdT2 + lane;   // + c*64 per step
        #pragma unroll 8
        for (int c = 0; c < 64; ++c) {
            const float2 wv = wrow[c << 6];                 // coalesced b64, L1-hot
            const float4 xv = *(const float4*)&xsT[c][hi0]; // uniform b128 broadcast
            a0[0] = __fmaf_rn(wv.x, xv.x, a0[0]); a1[0] = __fmaf_rn(wv.y, xv.x, a1[0]);
            a0[1] = __fmaf_rn(wv.x, xv.y, a0[1]); a1[1] = __fmaf_rn(wv.y, xv.y, a1[1]);
            a0[2] = __fmaf_rn(wv.x, xv.z, a0[2]); a1[2] = __fmaf_rn(wv.y, xv.z, a1[2]);
            a0[3] = __fmaf_rn(wv.x, xv.w, a0[3]); a1[3] = __fmaf_rn(wv.y, xv.w, a1[3]);
        }
        const float b0 = bd[lane];
        const float b1 = (lane < 59) ? bd[64 + lane] : 0.0f;
        #pragma unroll
        for (int k = 0; k < 4; ++k) {
            const int hi = hi0 + k;
            const float y0 = __fadd_rn(a0[k], b0);
            if (lane < 59) {
                yv[hi][lane] = y0;                               // depth logits
                ctxT[lane + 5][hi] = __fadd_rn(a1[k], b1);       // ctx ch 5..63
            } else {
                ctxT[lane - 59][hi] = y0;                        // ctx ch 0..4
            }
        }
    }
    // stage 3: softmax on wave-own rows (written by this wave; no barrier needed)
    for (int k = 0; k < 4; ++k) {
        const int hi = (wave << 2) | k;
        float v = (lane < Dc) ? yv[hi][lane] : -INFINITY;
        float m = v;
        #pragma unroll
        for (int off = 32; off; off >>= 1) m = fmaxf(m, __shfl_xor(m, off));
        float e = (lane < Dc) ? expf(__fsub_rn(v, m)) : 0.0f;
        float s = e;
        #pragma unroll
        for (int off = 32; off; off >>= 1) s = __fadd_rn(s, __shfl_xor(s, off));
        if (lane < Dc) yv[hi][lane] = __fdiv_rn(e, s);           // dep in place
    }
    __syncthreads();

    // stage 4: geometry for this block's d range, packed geo[dd][hi]
    {
        const float pt0 = post_trans[cam*3+0], pt1 = post_trans[cam*3+1], pt2 = post_trans[cam*3+2];
        const float tr0 = trans[cam*3+0],      tr1 = trans[cam*3+1],      tr2 = trans[cam*3+2];
        const float* M0 = camMat + (size_t)(cam*2 + 0)*18;  // FMA variant
        const float* M1 = camMat + (size_t)(cam*2 + 1)*18;  // non-FMA variant
        const float u = (float)(wi * (703.0 / 43.0));
        for (int idx = t; idx < 16*dn; idx += 256) {
            const int dd = idx >> 4, hi = idx & 15;          // coalesced geo write
            const int d = d0 + dd;
            const float v    = (float)(hi * 17.0);
            const float dval = (float)(1 + d);
            const int vA = geom_light<true >(M0, M0+9, pt0,pt1,pt2, tr0,tr1,tr2, u, v, dval, b);
            const int vB = geom_light<false>(M1, M1+9, pt0,pt1,pt2, tr0,tr1,tr2, u, v, dval, b);
            geo[dd][hi] = make_float4(yv[hi][d], __int_as_float(vA), __int_as_float(vB), 0.0f);
        }
    }
    __syncthreads();

    // stage 5: scatter with run-length aggregation over hi; ctx in registers
    {
        float cx[16];
        #pragma unroll
        for (int h = 0; h < 16; h += 2) {
            const float2 c2 = *(const float2*)&ctxT[lane][h];  // 2-way, free
            cx[h] = c2.x; cx[h+1] = c2.y;
        }
        for (int dd = wave; dd < dn; dd += 4) {
            int runVox = -1;
            float accv = 0.0f;
            #pragma unroll
            for (int hi = 0; hi < 16; ++hi) {
                const float4 g = geo[dd][hi];                  // uniform b128 broadcast
                const float dw = g.x;
                const int vA = __float_as_int(g.y);
                const int vB = __float_as_int(g.z);
                const float cxv = cx[hi];
                if (vA == vB) {
                    if (vA >= 0) {
                        if (vA != runVox) {
                            if (runVox >= 0) atomicAdd(&acc[((size_t)runVox << 6) + lane], accv);
                            runVox = vA; accv = 0.0f;
                        }
                        accv = __fadd_rn(accv, __fmul_rn(dw, cxv));
                    }
                } else {
                    const float hw = __fmul_rn(dw, 0.5f);
                    if (vA >= 0) {
                        if (vA != runVox) {
                            if (runVox >= 0) atomicAdd(&acc[((size_t)runVox << 6) + lane], accv);
                            runVox = vA; accv = 0.0f;
                        }
                        accv = __fadd_rn(accv, __fmul_rn(hw, cxv));
                    }
                    if (vB >= 0) atomicAdd(&acc[((size_t)vB << 6) + lane], __fmul_rn(hw, cxv));
                }
            }
            if (runVox >= 0) atomicAdd(&acc[((size_t)runVox << 6) + lane], accv);
        }
    }
}

// (b, pix, ch) -> (b, ch, pix) transpose, 64x64 tiles, float4 both directions
__global__ __launch_bounds__(256) void lss_transpose(
    const float* __restrict__ acc, float* __restrict__ out)
{
    __shared__ float tile[64][65];
    const int blk = blockIdx.x;
    const int b = blk >> 8;
    const int pixbase = (blk & 255) * 64;
    const float4* src4 = (const float4*)(acc + ((size_t)b*16384 + pixbase)*64);
    const int t = threadIdx.x;
    #pragma unroll
    for (int i = 0; i < 4; ++i) {
        const int e4 = i*256 + t;                 // 0..1023, coalesced 1KB/wave
        const float4 v = src4[e4];
        const int e = e4 << 2;
        const int r = e & 63, c = e >> 6;         // 4 consecutive rows, same col
        tile[r+0][c] = v.x; tile[r+1][c] = v.y; tile[r+2][c] = v.z; tile[r+3][c] = v.w;
    }
    __syncthreads();
    float* dst = out + (size_t)b*64*16384 + pixbase;
    #pragma unroll
    for (int i = 0; i < 4; ++i) {
        const int idx = i*256 + t;                // c = idx>>4, p-group = (idx&15)*4
        const int c = idx >> 4, p = (idx & 15) << 2;
        const float4 v = make_float4(tile[c][p], tile[c][p+1], tile[c][p+2], tile[c][p+3]);
        *(float4*)&dst[(size_t)c*16384 + p] = v;  // dwordx4, 256B/quarter-wave
    }
}

extern "C" void kernel_launch(void* const* d_in, const int* in_sizes, int n_in,
                              void* d_out, int out_size, void* d_ws, size_t ws_size,
                              hipStream_t stream) {
    const float* x          = (const float*)d_in[0];
    const float* rots       = (const float*)d_in[1];
    const float* trans      = (const float*)d_in[2];
    const float* intrins    = (const float*)d_in[3];
    const float* post_rots  = (const float*)d_in[4];
    const float* post_trans = (const float*)d_in[5];
    const float* wd         = (const float*)d_in[6];
    const float* bd         = (const float*)d_in[7];
    float* out = (float*)d_out;
    char* ws = (char*)d_ws;

    float* acc    = (float*)(ws + WS_ACC);
    float* camMat = (float*)(ws + WS_CAM);
    float* wdT2   = (float*)(ws + WS_WDT);

    prep<<<dim3(2048), dim3(256), 0, stream>>>(
        wd, rots, intrins, post_rots, wdT2, camMat, (float4*)acc);
    lss_main<<<dim3(NBLK2), dim3(256), 0, stream>>>(
        x, trans, post_trans, bd, wdT2, camMat, acc);
    lss_transpose<<<dim3(Bc*256), dim3(256), 0, stream>>>(acc, out);
}

// Round 15
// 185.034 us; speedup vs baseline: 1.1889x; 1.1889x over previous
//
#include <hip/hip_runtime.h>
#include <math.h>

#define Bc 4
#define Nc 6
#define Dc 59
#define FHc 16
#define FWc 44
#define Cc 64
#define OCc 123   // D + OUT_C
#define NXc 128
#define NYc 128
#define NVOX (Bc*NXc*NYc)         // 65536
#define NBLK (Bc*Nc*FWc)          // 1056 blocks = (cam, wi)

// ws layout: acc[65536][64] f32 (16 MB); camMat[24][2][18]; wdT2[64][128] interleaved
#define WS_ACC 0
#define WS_CAM ((size_t)16777216)
#define WS_WDT ((size_t)16781312)

template<bool FMA>
__device__ __forceinline__ float mulsub(float a, float b, float c) {
    if (FMA) return __fmaf_rn(-a, b, c);
    return __fadd_rn(c, __fmul_rn(-a, b));
}

// numpy.linalg.inv mirror: LAPACK sgesv on the C-order buffer seen as Fortran,
// i.e. factorizes A^T (inv(A) = inv(A^T)^T). sgetf2+sgetrs, strict f32.
template<bool FMA>
__device__ __forceinline__ void lu_inv3x3T(const float* __restrict__ m, float* __restrict__ o) {
    float A[3][3] = {{m[0],m[3],m[6]},{m[1],m[4],m[7]},{m[2],m[5],m[8]}};  // A^T
    int piv0, piv1;
    {
        float a0=fabsf(A[0][0]), a1=fabsf(A[1][0]), a2=fabsf(A[2][0]);
        int p = 0; float mx = a0;
        if (a1 > mx) { mx = a1; p = 1; }
        if (a2 > mx) { mx = a2; p = 2; }
        piv0 = p;
        if (p != 0) { for (int k=0;k<3;++k){ float t=A[0][k]; A[0][k]=A[p][k]; A[p][k]=t; } }
        const float d = __fdiv_rn(1.0f, A[0][0]);
        A[1][0] = __fmul_rn(A[1][0], d);
        A[2][0] = __fmul_rn(A[2][0], d);
        #pragma unroll
        for (int i=1;i<3;++i)
            #pragma unroll
            for (int j=1;j<3;++j)
                A[i][j] = mulsub<FMA>(A[i][0], A[0][j], A[i][j]);
    }
    {
        float a1=fabsf(A[1][1]), a2=fabsf(A[2][1]);
        int p = (a2 > a1) ? 2 : 1;
        piv1 = p;
        if (p != 1) { for (int k=0;k<3;++k){ float t=A[1][k]; A[1][k]=A[p][k]; A[p][k]=t; } }
        const float d = __fdiv_rn(1.0f, A[1][1]);
        A[2][1] = __fmul_rn(A[2][1], d);
        A[2][2] = mulsub<FMA>(A[2][1], A[1][2], A[2][2]);
    }
    float B[3][3] = {{1.f,0.f,0.f},{0.f,1.f,0.f},{0.f,0.f,1.f}};
    if (piv0 != 0) { for (int k=0;k<3;++k){ float t=B[0][k]; B[0][k]=B[piv0][k]; B[piv0][k]=t; } }
    if (piv1 != 1) { for (int k=0;k<3;++k){ float t=B[1][k]; B[1][k]=B[piv1][k]; B[piv1][k]=t; } }
    #pragma unroll
    for (int j=0;j<3;++j) {
        B[1][j] = mulsub<FMA>(A[1][0], B[0][j], B[1][j]);
        B[2][j] = mulsub<FMA>(A[2][0], B[0][j], B[2][j]);
        B[2][j] = mulsub<FMA>(A[2][1], B[1][j], B[2][j]);
        B[2][j] = __fdiv_rn(B[2][j], A[2][2]);
        B[0][j] = mulsub<FMA>(A[0][2], B[2][j], B[0][j]);
        B[1][j] = mulsub<FMA>(A[1][2], B[2][j], B[1][j]);
        B[1][j] = __fdiv_rn(B[1][j], A[1][1]);
        B[0][j] = mulsub<FMA>(A[0][1], B[1][j], B[0][j]);
        B[0][j] = __fdiv_rn(B[0][j], A[0][0]);
    }
    o[0]=B[0][0]; o[1]=B[1][0]; o[2]=B[2][0];
    o[3]=B[0][1]; o[4]=B[1][1]; o[5]=B[2][1];
    o[6]=B[0][2]; o[7]=B[1][2]; o[8]=B[2][2];
}

template<bool FMA>
__device__ __forceinline__ float dot3(float a0,float a1,float a2,float b0,float b1,float b2){
    if (FMA) return __fmaf_rn(a2,b2, __fmaf_rn(a1,b1, __fmul_rn(a0,b0)));
    return __fadd_rn(__fadd_rn(__fmul_rn(a0,b0), __fmul_rn(a1,b1)), __fmul_rn(a2,b2));
}

// ---- K0: acc zeroing (full-BW float4) + wd interleave + per-(cam,var) matrices ----
// wdT2[c][2*o] = wd[o][c] (o 0..63); wdT2[c][2*o+1] = wd[o+64][c] (o 0..58), pads 0
__global__ __launch_bounds__(256) void prep(
    const float* __restrict__ wd, const float* __restrict__ rots,
    const float* __restrict__ intrins, const float* __restrict__ post_rots,
    float* __restrict__ wdT2, float* __restrict__ camMat, float4* __restrict__ acc4)
{
    const int gid = blockIdx.x*256 + threadIdx.x;   // 0..524287 (2048 blocks)
    const float4 z = make_float4(0.f, 0.f, 0.f, 0.f);
    acc4[gid] = z;
    acc4[gid + 524288] = z;                         // 2 x 524288 = 1M float4 = 16 MB

    if (gid < OCc*Cc) {
        const int o = gid >> 6, c = gid & 63;
        const int slot = (o < 64) ? (o << 1) : (((o - 64) << 1) | 1);
        wdT2[(c << 7) + slot] = wd[gid];
    } else if (gid < OCc*Cc + 320) {
        const int k = gid - OCc*Cc;                 // zero 5 pad slots per c
        const int c = k / 5, o = 59 + (k % 5);
        wdT2[(c << 7) + (o << 1) + 1] = 0.0f;
    }
    if (gid < 48) {
        const int cam = gid >> 1;
        const int var = gid & 1;
        const float* pr = post_rots + cam*9;
        const float* ro = rots      + cam*9;
        const float* it = intrins   + cam*9;
        float PRi[9], INi[9], CM[9];
        if (var == 0) { lu_inv3x3T<true >(pr, PRi); lu_inv3x3T<true >(it, INi); }
        else          { lu_inv3x3T<false>(pr, PRi); lu_inv3x3T<false>(it, INi); }
        #pragma unroll
        for (int r2 = 0; r2 < 3; ++r2)
            #pragma unroll
            for (int c2 = 0; c2 < 3; ++c2)
                CM[r2*3+c2] = dot3<true>(ro[r2*3+0], ro[r2*3+1], ro[r2*3+2],
                                         INi[0*3+c2], INi[1*3+c2], INi[2*3+c2]);
        float* dst = camMat + (size_t)(cam*2 + var)*18;
        #pragma unroll
        for (int k = 0; k < 9; ++k) { dst[k] = PRi[k]; dst[9+k] = CM[k]; }
    }
}

// Per-point geometry using precomputed PRi/CM (ops identical to R6 path)
template<bool FMA>
__device__ __forceinline__ int geom_light(
    const float* __restrict__ PRi, const float* __restrict__ CM,
    float pt0, float pt1, float pt2, float tr0, float tr1, float tr2,
    float u, float v, float dval, int b)
{
    const float p0 = __fsub_rn(u,    pt0);
    const float p1 = __fsub_rn(v,    pt1);
    const float p2 = __fsub_rn(dval, pt2);
    const float q0 = dot3<FMA>(PRi[0],PRi[1],PRi[2], p0,p1,p2);
    const float q1 = dot3<FMA>(PRi[3],PRi[4],PRi[5], p0,p1,p2);
    const float q2 = dot3<FMA>(PRi[6],PRi[7],PRi[8], p0,p1,p2);
    const float r0 = __fmul_rn(q0, q2);
    const float r1 = __fmul_rn(q1, q2);
    const float s0 = __fadd_rn(dot3<FMA>(CM[0],CM[1],CM[2], r0,r1,q2), tr0);
    const float s1 = __fadd_rn(dot3<FMA>(CM[3],CM[4],CM[5], r0,r1,q2), tr1);
    const float s2 = __fadd_rn(dot3<FMA>(CM[6],CM[7],CM[8], r0,r1,q2), tr2);
    const float CX  = -51.200000762939453f;  // f32(f32(-50.8) - f32(0.8)/2)
    const float DXf =  0.80000001192092896f; // f32(0.8)
    const float gx = __fdiv_rn(__fsub_rn(s0, CX), DXf);
    const float gy = __fdiv_rn(__fsub_rn(s1, CX), DXf);
    const float gz = __fdiv_rn(__fsub_rn(s2, -10.0f), 20.0f);
    const bool kept = (gx > -1.0f) && (gx < 128.0f) &&
                      (gy > -1.0f) && (gy < 128.0f) &&
                      (gz > -1.0f) && (gz < 1.0f);
    return kept ? (b*(NXc*NYc) + ((int)gy)*NXc + (int)gx) : -1;
}

// ---- K1: one block per (cam, wi), 512 threads (8 waves) — same work as R12's
// 256-thread version split over 2x the waves (no duplication): 33 waves/CU.
__global__ __launch_bounds__(512, 8) void lss_main(
    const float* __restrict__ x, const float* __restrict__ trans,
    const float* __restrict__ post_trans, const float* __restrict__ bd,
    const float* __restrict__ wdT2, const float* __restrict__ camMat,
    float* __restrict__ acc)
{
    const int blk = blockIdx.x;
    const int wi  = blk % FWc;
    const int cam = blk / FWc;        // 0..23
    const int b   = cam / Nc;
    const int t = threadIdx.x;
    const int wave = t >> 6, lane = t & 63;   // wave 0..7

    __shared__ float  xsT[64][16];    // c-major x column            (4 KB)
    __shared__ float  yv[16][60];     // y then dep in place         (3.8 KB)
    __shared__ float  ctxT[64][18];   // ch-major ctx, pad 18        (4.6 KB)
    __shared__ float4 geo[Dc][16];    // (dep, vA, vB, -) per point  (15.1 KB)

    // stage 1: x column gather (c-major so stage-2 can b64-broadcast 2 rows)
    {
        const float* xb = x + (size_t)cam*64*(FHc*FWc) + wi;
        for (int idx = t; idx < 1024; idx += 512) {
            const int c = idx >> 4, hi = idx & 15;
            xsT[c][hi] = xb[(size_t)c*(FHc*FWc) + hi*FWc];
        }
    }
    __syncthreads();

    // stage 2: matvec; wave handles rows hi0, hi0+1; lane = o and o+64
    // one b64 global load per c (interleaved layout); FMA chain ascending ->
    // bit-identical per-output sum order vs all previous rounds
    {
        const int hi0 = wave << 1;
        float a0[2] = {0.f,0.f}, a1[2] = {0.f,0.f};
        const float2* wrow = (const float2*)wdT2 + lane;   // + c*64 per step
        #pragma unroll 8
        for (int c = 0; c < 64; ++c) {
            const float2 wv = wrow[c << 6];                 // coalesced b64, L1-hot
            const float2 xv = *(const float2*)&xsT[c][hi0]; // uniform b64 broadcast
            a0[0] = __fmaf_rn(wv.x, xv.x, a0[0]); a1[0] = __fmaf_rn(wv.y, xv.x, a1[0]);
            a0[1] = __fmaf_rn(wv.x, xv.y, a0[1]); a1[1] = __fmaf_rn(wv.y, xv.y, a1[1]);
        }
        const float b0 = bd[lane];
        const float b1 = (lane < 59) ? bd[64 + lane] : 0.0f;
        #pragma unroll
        for (int k = 0; k < 2; ++k) {
            const int hi = hi0 + k;
            const float y0 = __fadd_rn(a0[k], b0);
            if (lane < 59) {
                yv[hi][lane] = y0;                               // depth logits
                ctxT[lane + 5][hi] = __fadd_rn(a1[k], b1);       // ctx ch 5..63
            } else {
                ctxT[lane - 59][hi] = y0;                        // ctx ch 0..4
            }
        }
    }
    // stage 3: softmax on wave-own rows (written by this wave; no barrier needed)
    for (int k = 0; k < 2; ++k) {
        const int hi = (wave << 1) | k;
        float v = (lane < Dc) ? yv[hi][lane] : -INFINITY;
        float m = v;
        #pragma unroll
        for (int off = 32; off; off >>= 1) m = fmaxf(m, __shfl_xor(m, off));
        float e = (lane < Dc) ? expf(__fsub_rn(v, m)) : 0.0f;
        float s = e;
        #pragma unroll
        for (int off = 32; off; off >>= 1) s = __fadd_rn(s, __shfl_xor(s, off));
        if (lane < Dc) yv[hi][lane] = __fdiv_rn(e, s);           // dep in place
    }
    __syncthreads();

    // stage 4: geometry, packed records geo[d][hi] = (dep, vA, vB, 0)
    {
        const float pt0 = post_trans[cam*3+0], pt1 = post_trans[cam*3+1], pt2 = post_trans[cam*3+2];
        const float tr0 = trans[cam*3+0],      tr1 = trans[cam*3+1],      tr2 = trans[cam*3+2];
        const float* M0 = camMat + (size_t)(cam*2 + 0)*18;  // FMA variant
        const float* M1 = camMat + (size_t)(cam*2 + 1)*18;  // non-FMA variant
        const float u = (float)(wi * (703.0 / 43.0));
        for (int idx = t; idx < 16*Dc; idx += 512) {
            const int d = idx >> 4, hi = idx & 15;           // coalesced geo write
            const float v    = (float)(hi * 17.0);
            const float dval = (float)(1 + d);
            const int vA = geom_light<true >(M0, M0+9, pt0,pt1,pt2, tr0,tr1,tr2, u, v, dval, b);
            const int vB = geom_light<false>(M1, M1+9, pt0,pt1,pt2, tr0,tr1,tr2, u, v, dval, b);
            geo[d][hi] = make_float4(yv[hi][d], __int_as_float(vA), __int_as_float(vB), 0.0f);
        }
    }
    __syncthreads();

    // stage 5: scatter with run-length aggregation over hi; ctx in registers
    {
        float cx[16];
        #pragma unroll
        for (int h = 0; h < 16; h += 2) {
            const float2 c2 = *(const float2*)&ctxT[lane][h];  // 2-way, free
            cx[h] = c2.x; cx[h+1] = c2.y;
        }
        for (int d = wave; d < Dc; d += 8) {
            int runVox = -1;
            float accv = 0.0f;
            #pragma unroll
            for (int hi = 0; hi < 16; ++hi) {
                const float4 g = geo[d][hi];                   // uniform b128 broadcast
                const float dw = g.x;
                const int vA = __float_as_int(g.y);
                const int vB = __float_as_int(g.z);
                const float cxv = cx[hi];
                if (vA == vB) {
                    if (vA >= 0) {
                        if (vA != runVox) {
                            if (runVox >= 0) atomicAdd(&acc[((size_t)runVox << 6) + lane], accv);
                            runVox = vA; accv = 0.0f;
                        }
                        accv = __fadd_rn(accv, __fmul_rn(dw, cxv));
                    }
                } else {
                    const float hw = __fmul_rn(dw, 0.5f);
                    if (vA >= 0) {
                        if (vA != runVox) {
                            if (runVox >= 0) atomicAdd(&acc[((size_t)runVox << 6) + lane], accv);
                            runVox = vA; accv = 0.0f;
                        }
                        accv = __fadd_rn(accv, __fmul_rn(hw, cxv));
                    }
                    if (vB >= 0) atomicAdd(&acc[((size_t)vB << 6) + lane], __fmul_rn(hw, cxv));
                }
            }
            if (runVox >= 0) atomicAdd(&acc[((size_t)runVox << 6) + lane], accv);
        }
    }
}

// (b, pix, ch) -> (b, ch, pix) transpose, 64x64 tiles, float4 both directions
__global__ __launch_bounds__(256) void lss_transpose(
    const float* __restrict__ acc, float* __restrict__ out)
{
    __shared__ float tile[64][65];
    const int blk = blockIdx.x;
    const int b = blk >> 8;
    const int pixbase = (blk & 255) * 64;
    const float4* src4 = (const float4*)(acc + ((size_t)b*16384 + pixbase)*64);
    const int t = threadIdx.x;
    #pragma unroll
    for (int i = 0; i < 4; ++i) {
        const int e4 = i*256 + t;                 // 0..1023, coalesced 1KB/wave
        const float4 v = src4[e4];
        const int e = e4 << 2;
        const int r = e & 63, c = e >> 6;         // 4 consecutive rows, same col
        tile[r+0][c] = v.x; tile[r+1][c] = v.y; tile[r+2][c] = v.z; tile[r+3][c] = v.w;
    }
    __syncthreads();
    float* dst = out + (size_t)b*64*16384 + pixbase;
    #pragma unroll
    for (int i = 0; i < 4; ++i) {
        const int idx = i*256 + t;                // c = idx>>4, p-group = (idx&15)*4
        const int c = idx >> 4, p = (idx & 15) << 2;
        const float4 v = make_float4(tile[c][p], tile[c][p+1], tile[c][p+2], tile[c][p+3]);
        *(float4*)&dst[(size_t)c*16384 + p] = v;  // dwordx4, 256B/quarter-wave
    }
}

extern "C" void kernel_launch(void* const* d_in, const int* in_sizes, int n_in,
                              void* d_out, int out_size, void* d_ws, size_t ws_size,
                              hipStream_t stream) {
    const float* x          = (const float*)d_in[0];
    const float* rots       = (const float*)d_in[1];
    const float* trans      = (const float*)d_in[2];
    const float* intrins    = (const float*)d_in[3];
    const float* post_rots  = (const float*)d_in[4];
    const float* post_trans = (const float*)d_in[5];
    const float* wd         = (const float*)d_in[6];
    const float* bd         = (const float*)d_in[7];
    float* out = (float*)d_out;
    char* ws = (char*)d_ws;

    float* acc    = (float*)(ws + WS_ACC);
    float* camMat = (float*)(ws + WS_CAM);
    float* wdT2   = (float*)(ws + WS_WDT);

    prep<<<dim3(2048), dim3(256), 0, stream>>>(
        wd, rots, intrins, post_rots, wdT2, camMat, (float4*)acc);
    lss_main<<<dim3(NBLK), dim3(512), 0, stream>>>(
        x, trans, post_trans, bd, wdT2, camMat, acc);
    lss_transpose<<<dim3(Bc*256), dim3(256), 0, stream>>>(acc, out);
}